// Round 1
// baseline (199.159 us; speedup 1.0000x reference)
//
#include <hip/hip_runtime.h>
#include <math.h>

#define BINS 10

// Problem constants (from reference): BATCH=8388608, NUM_CLASSES=2
constexpr int   NPAIRS  = 4194304;      // BATCH/2 rows handled per float4 (2 rows x 2 classes)
constexpr float NTOT_F  = 16777216.0f;  // BATCH * NUM_CLASSES

constexpr int G1  = 1024;   // histogram blocks
constexpr int G2  = 2048;   // weighted-sum blocks
constexpr int BLK = 256;

// Workspace layout (bytes). Everything written before read -> no memset needed.
constexpr size_t WS_HIST = 0;        // G1*BINS u32   = 40960 B
constexpr size_t WS_BETA = 40960;    // BINS f32      = 40 B
constexpr size_t WS_PART = 41600;    // G2 f64        = 16384 B  (8-aligned)

__device__ __forceinline__ int bin_of(float x, float y) {
    float s = 1.0f / (1.0f + __expf(-x));
    float g = fabsf(s - y);
    int b = (int)(g * 9.9999f);      // g in [0,1] -> [0,9]; floor via trunc (g>=0)
    return b < 9 ? b : 9;
}

// Pass 1: ballot-based histogram, no atomics.
// NPAIRS / (G1*BLK) = 16 exactly -> no tail divergence, counts are wave-uniform.
__global__ __launch_bounds__(BLK) void ghm_hist(const float4* __restrict__ x4,
                                                const int2*   __restrict__ t2,
                                                unsigned*     __restrict__ blk_hist) {
    unsigned cnt[BINS];
#pragma unroll
    for (int b = 0; b < BINS; ++b) cnt[b] = 0;

    const int stride = gridDim.x * blockDim.x;
    for (int i = blockIdx.x * blockDim.x + threadIdx.x; i < NPAIRS; i += stride) {
        float4 xv = x4[i];
        int2   tv = t2[i];
        int b0 = bin_of(xv.x, tv.x == 0 ? 1.0f : 0.0f);
        int b1 = bin_of(xv.y, tv.x == 1 ? 1.0f : 0.0f);
        int b2 = bin_of(xv.z, tv.y == 0 ? 1.0f : 0.0f);
        int b3 = bin_of(xv.w, tv.y == 1 ? 1.0f : 0.0f);
#pragma unroll
        for (int b = 0; b < BINS; ++b) {
            cnt[b] += __popcll(__ballot(b0 == b)) + __popcll(__ballot(b1 == b))
                    + __popcll(__ballot(b2 == b)) + __popcll(__ballot(b3 == b));
        }
    }

    __shared__ unsigned lds[BLK / 64][BINS];
    const int wave = threadIdx.x >> 6;
    const int lane = threadIdx.x & 63;
    if (lane == 0) {
#pragma unroll
        for (int b = 0; b < BINS; ++b) lds[wave][b] = cnt[b];  // lane 0 always ran every iter
    }
    __syncthreads();
    if (threadIdx.x < BINS) {
        unsigned t = lds[0][threadIdx.x] + lds[1][threadIdx.x]
                   + lds[2][threadIdx.x] + lds[3][threadIdx.x];
        blk_hist[blockIdx.x * BINS + threadIdx.x] = t;
    }
}

// Reduce per-block histograms, compute beta[10].
__global__ __launch_bounds__(BLK) void ghm_beta(const unsigned* __restrict__ blk_hist,
                                                float*          __restrict__ beta) {
    __shared__ unsigned tot[BINS];
    if (threadIdx.x < BINS) tot[threadIdx.x] = 0;
    __syncthreads();

    unsigned loc[BINS];
#pragma unroll
    for (int b = 0; b < BINS; ++b) loc[b] = 0;
    for (int g = threadIdx.x; g < G1; g += BLK) {
#pragma unroll
        for (int b = 0; b < BINS; ++b) loc[b] += blk_hist[g * BINS + b];
    }
#pragma unroll
    for (int b = 0; b < BINS; ++b) atomicAdd(&tot[b], loc[b]);
    __syncthreads();

    if (threadIdx.x < BINS) {
        float nonempty = 0.0f;
#pragma unroll
        for (int b = 0; b < BINS; ++b) nonempty += (tot[b] > 0u) ? 1.0f : 0.0f;
        float gd = fmaxf((float)tot[threadIdx.x] * nonempty, 0.0001f);
        beta[threadIdx.x] = NTOT_F / gd;   // matches reference fp32 arithmetic
    }
}

// Pass 2: weighted BCE sum, per-block double partials (deterministic, no atomics).
__global__ __launch_bounds__(BLK) void ghm_wsum(const float4* __restrict__ x4,
                                                const int2*   __restrict__ t2,
                                                const float*  __restrict__ beta,
                                                double*       __restrict__ part) {
    __shared__ float bsh[BINS];
    if (threadIdx.x < BINS) bsh[threadIdx.x] = beta[threadIdx.x];
    __syncthreads();

    double acc = 0.0;
    const int stride = gridDim.x * blockDim.x;
    for (int i = blockIdx.x * blockDim.x + threadIdx.x; i < NPAIRS; i += stride) {
        float4 xv = x4[i];
        int2   tv = t2[i];
        float xs[4] = {xv.x, xv.y, xv.z, xv.w};
        float ys[4] = {tv.x == 0 ? 1.0f : 0.0f, tv.x == 1 ? 1.0f : 0.0f,
                       tv.y == 0 ? 1.0f : 0.0f, tv.y == 1 ? 1.0f : 0.0f};
        float psum = 0.0f;
#pragma unroll
        for (int k = 0; k < 4; ++k) {
            float x = xs[k], y = ys[k];
            float s = 1.0f / (1.0f + __expf(-x));   // same sigmoid as pass 1 -> consistent bins
            float g = fabsf(s - y);
            int b = (int)(g * 9.9999f);
            b = b < 9 ? b : 9;
            float w   = bsh[b];
            float bce = fmaxf(x, 0.0f) - x * y + log1pf(__expf(-fabsf(x)));
            psum += w * bce;
        }
        acc += (double)psum;
    }

    // wave shuffle reduce (64 lanes), then cross-wave via LDS
    for (int off = 32; off > 0; off >>= 1) acc += __shfl_down(acc, off, 64);
    __shared__ double wsum[BLK / 64];
    const int wave = threadIdx.x >> 6;
    const int lane = threadIdx.x & 63;
    if (lane == 0) wsum[wave] = acc;
    __syncthreads();
    if (threadIdx.x == 0)
        part[blockIdx.x] = wsum[0] + wsum[1] + wsum[2] + wsum[3];
}

// Final: reduce G2 doubles, divide by N, write scalar.
__global__ __launch_bounds__(BLK) void ghm_final(const double* __restrict__ part,
                                                 float*        __restrict__ out) {
    double acc = 0.0;
    for (int i = threadIdx.x; i < G2; i += BLK) acc += part[i];
    for (int off = 32; off > 0; off >>= 1) acc += __shfl_down(acc, off, 64);
    __shared__ double wsum[BLK / 64];
    const int wave = threadIdx.x >> 6;
    const int lane = threadIdx.x & 63;
    if (lane == 0) wsum[wave] = acc;
    __syncthreads();
    if (threadIdx.x == 0) {
        double s = wsum[0] + wsum[1] + wsum[2] + wsum[3];
        out[0] = (float)(s / (double)NTOT_F);
    }
}

extern "C" void kernel_launch(void* const* d_in, const int* in_sizes, int n_in,
                              void* d_out, int out_size, void* d_ws, size_t ws_size,
                              hipStream_t stream) {
    const float4* x4 = (const float4*)d_in[0];     // [B,2] fp32, read as 2 rows / float4
    const int2*   t2 = (const int2*)d_in[1];       // int32 targets, 2 rows / int2

    unsigned* blk_hist = (unsigned*)((char*)d_ws + WS_HIST);
    float*    beta     = (float*)   ((char*)d_ws + WS_BETA);
    double*   part     = (double*)  ((char*)d_ws + WS_PART);
    float*    out      = (float*)d_out;

    ghm_hist <<<G1, BLK, 0, stream>>>(x4, t2, blk_hist);
    ghm_beta <<<1,  BLK, 0, stream>>>(blk_hist, beta);
    ghm_wsum <<<G2, BLK, 0, stream>>>(x4, t2, beta, part);
    ghm_final<<<1,  BLK, 0, stream>>>(part, out);
}

// Round 2
// 122.036 us; speedup vs baseline: 1.6320x; 1.6320x over previous
//
#include <hip/hip_runtime.h>
#include <math.h>

#define BINS 10

// Problem constants: BATCH=8388608, NUM_CLASSES=2
constexpr int   NPAIRS = 4194304;       // float4 quads (2 rows x 2 classes each)
constexpr float NTOT_F = 16777216.0f;   // BATCH * NUM_CLASSES

constexpr int G1  = 1024;               // main-kernel blocks; NPAIRS/(G1*256) = 16 iters exactly
constexpr int BLK = 256;

// Workspace layout (all written before read; no memset needed):
//   blk_sum: [BINS][G1] float at byte 0      (40960 B)  -- per-block per-bin sum of log2(1+e^z)
//   blk_cnt: [BINS][G1] uint  at byte 40960  (40960 B)  -- per-block per-bin element counts
constexpr size_t WS_SUM = 0;
constexpr size_t WS_CNT = 40960;

__device__ __forceinline__ void proc(float x, bool y1, int tid,
                                     float* __restrict__ lsum,
                                     unsigned* __restrict__ lcnt) {
    // z = (y==1) ? -x : x ;  t = e^z ; u = 1+t
    // g = |sigmoid(x)-y| = t/u ;  bce = max(x,0)-x*y+log1p(e^-|x|) = ln(u)
    float z = y1 ? -x : x;
    float t = __builtin_amdgcn_exp2f(z * 1.4426950408889634f);  // e^z
    float u = 1.0f + t;
    float g = t * __builtin_amdgcn_rcpf(u);
    int   b = (int)(g * 9.9999f);          // g in [0,1] -> floor==trunc; < 10 always
    b = b < 9 ? b : 9;                      // safety clamp
    float l = __builtin_amdgcn_logf(u);     // log2(u); multiply by ln2 once at the very end
    lsum[b * BLK + tid] += l;
    lcnt[b * BLK + tid] += 1u;
}

// Single data pass: per-block per-bin (count, log2-bce-sum).
// LDS columns: lds[bin*256 + tid] -> bank = tid%32 regardless of bin
// (2 lanes/bank aliasing only, which is free on gfx950 per m136).
__global__ __launch_bounds__(BLK) void ghm_main(const float4* __restrict__ x4,
                                                const int2*   __restrict__ t2,
                                                float*        __restrict__ blk_sum,
                                                unsigned*     __restrict__ blk_cnt) {
    __shared__ float    lsum[BINS * BLK];   // 10240 B
    __shared__ unsigned lcnt[BINS * BLK];   // 10240 B
    const int tid = threadIdx.x;

#pragma unroll
    for (int b = 0; b < BINS; ++b) {
        lsum[b * BLK + tid] = 0.0f;
        lcnt[b * BLK + tid] = 0u;
    }
    // no barrier needed: each thread touches only its own column until the reduce

    const int stride = gridDim.x * blockDim.x;
    for (int i = blockIdx.x * BLK + tid; i < NPAIRS; i += stride) {
        float4 xv = x4[i];
        int2   tv = t2[i];
        // element (row, c): y = (target[row] == c)
        proc(xv.x, tv.x == 0, tid, lsum, lcnt);
        proc(xv.y, tv.x == 1, tid, lsum, lcnt);
        proc(xv.z, tv.y == 0, tid, lsum, lcnt);
        proc(xv.w, tv.y == 1, tid, lsum, lcnt);
    }

    __syncthreads();
    const int wave = tid >> 6;
    const int lane = tid & 63;
    // wave w reduces bins {w, w+4, w+8}: 4 strided LDS reads + 64-lane shuffle tree
    for (int b = wave; b < BINS; b += 4) {
        float    s = lsum[b * BLK + lane]       + lsum[b * BLK + lane + 64]
                   + lsum[b * BLK + lane + 128] + lsum[b * BLK + lane + 192];
        unsigned c = lcnt[b * BLK + lane]       + lcnt[b * BLK + lane + 64]
                   + lcnt[b * BLK + lane + 128] + lcnt[b * BLK + lane + 192];
        for (int off = 32; off > 0; off >>= 1) {
            s += __shfl_down(s, off, 64);
            c += __shfl_down(c, off, 64);
        }
        if (lane == 0) {
            blk_sum[b * G1 + blockIdx.x] = s;   // bin-major -> contiguous for final kernel
            blk_cnt[b * G1 + blockIdx.x] = c;
        }
    }
}

// Final: 10 waves, wave w reduces bin w's G1 partials; lane/wave shuffle trees;
// then thread 0 forms beta and the weighted total. Deterministic, no atomics.
__global__ __launch_bounds__(640) void ghm_final(const float*    __restrict__ blk_sum,
                                                 const unsigned* __restrict__ blk_cnt,
                                                 float*          __restrict__ out) {
    const int wave = threadIdx.x >> 6;   // 0..9 = bin
    const int lane = threadIdx.x & 63;
    double s = 0.0, c = 0.0;
    for (int g = lane; g < G1; g += 64) {
        s += (double)blk_sum[wave * G1 + g];
        c += (double)blk_cnt[wave * G1 + g];
    }
    for (int off = 32; off > 0; off >>= 1) {
        s += __shfl_down(s, off, 64);
        c += __shfl_down(c, off, 64);
    }
    __shared__ double Sb[BINS], Cb[BINS];
    if (lane == 0) { Sb[wave] = s; Cb[wave] = c; }
    __syncthreads();
    if (threadIdx.x == 0) {
        float nonempty = 0.0f;
#pragma unroll
        for (int b = 0; b < BINS; ++b) nonempty += (Cb[b] > 0.0) ? 1.0f : 0.0f;
        double tot = 0.0;
#pragma unroll
        for (int b = 0; b < BINS; ++b) {
            float gd   = fmaxf((float)Cb[b] * nonempty, 0.0001f);  // ref fp32 arithmetic
            float beta = NTOT_F / gd;
            tot += (double)beta * Sb[b];
        }
        // bce sums were kept in log2; apply ln2 once, then mean
        out[0] = (float)(tot * 0.693147180559945309 / (double)NTOT_F);
    }
}

extern "C" void kernel_launch(void* const* d_in, const int* in_sizes, int n_in,
                              void* d_out, int out_size, void* d_ws, size_t ws_size,
                              hipStream_t stream) {
    const float4* x4 = (const float4*)d_in[0];   // [B,2] fp32 -> 2 rows per float4
    const int2*   t2 = (const int2*)d_in[1];     // int targets -> 2 rows per int2

    float*    blk_sum = (float*)   ((char*)d_ws + WS_SUM);
    unsigned* blk_cnt = (unsigned*)((char*)d_ws + WS_CNT);
    float*    out     = (float*)d_out;

    ghm_main <<<G1, BLK, 0, stream>>>(x4, t2, blk_sum, blk_cnt);
    ghm_final<<<1, 640, 0, stream>>>(blk_sum, blk_cnt, out);
}